// Round 4
// baseline (475.568 us; speedup 1.0000x reference)
//
#include <hip/hip_runtime.h>

#define S_LEN 2048
#define D_DIM 128
#define BQ 64
#define BK 32
#define NITER (S_LEN / BK)   // 64

typedef float f32x4 __attribute__((ext_vector_type(4)));
typedef short s16x8 __attribute__((ext_vector_type(8)));
typedef unsigned int u32;

#if __has_builtin(__builtin_amdgcn_exp2f)
#define EXP2(x) __builtin_amdgcn_exp2f(x)
#else
#define EXP2(x) exp2f(x)
#endif

// pack two floats' bf16 (truncated) into one u32: x1 in upper 16, x0 in lower
__device__ __forceinline__ u32 pack_trunc(float x0, float x1) {
    return __builtin_amdgcn_perm(__float_as_uint(x1), __float_as_uint(x0), 0x07060302u);
}
// round-to-nearest bf16 pack
__device__ __forceinline__ u32 pack_rne(float x0, float x1) {
    return __builtin_amdgcn_perm(__float_as_uint(x1) + 0x8000u,
                                 __float_as_uint(x0) + 0x8000u, 0x07060302u);
}

#define GLOAD16(g, l) \
    __builtin_amdgcn_global_load_lds((const __attribute__((address_space(1))) u32*)(g), \
                                     (__attribute__((address_space(3))) u32*)(l), 16, 0, 0)

// ---- DPP 16-lane row reductions (VALU pipe, no LDS) ----
template <int CTRL>
__device__ __forceinline__ float dppmov(float x) {
    return __int_as_float(__builtin_amdgcn_update_dpp(0, __float_as_int(x), CTRL, 0xF, 0xF, true));
}
__device__ __forceinline__ float row_max16(float x) {
    x = fmaxf(x, dppmov<0xB1>(x));    // xor1: quad_perm(1,0,3,2)
    x = fmaxf(x, dppmov<0x4E>(x));    // xor2: quad_perm(2,3,0,1)
    x = fmaxf(x, dppmov<0x141>(x));   // xor7: row_half_mirror
    x = fmaxf(x, dppmov<0x140>(x));   // xor15: row_mirror
    return x;
}
__device__ __forceinline__ float row_sum16(float x) {
    x += dppmov<0xB1>(x);
    x += dppmov<0x4E>(x);
    x += dppmov<0x141>(x);
    x += dppmov<0x140>(x);
    return x;
}

// ---------------- fused pre-pass ----------------
// blocks [0,4096): K -> hi/lo bf16, tiled + XOR-swizzled 16B units
//   Kc layout: [bh][kt][r=0..31][u'=0..31][8 ushorts]; u = 2c (hi)/2c+1 (lo); u' = u^(r&7).
// blocks [4096,5120): V -> transposed bf16 tiles Vt[bh][kt][d][kk]
__global__ void prep_kv(const float* __restrict__ K, const float* __restrict__ V,
                        unsigned short* __restrict__ Kc, unsigned short* __restrict__ Vt) {
    if (blockIdx.x < 4096) {
        const int t  = blockIdx.x * 256 + threadIdx.x;   // 2^20 threads
        const int c  = t & 15;
        const int s  = (t >> 4) & (S_LEN - 1);
        const int bh = t >> 15;
        const float* src = K + ((size_t)bh * S_LEN + s) * D_DIM + c * 8;
        const float4 a = *(const float4*)src;
        const float4 b = *(const float4*)(src + 4);
        const float x[8] = {a.x,a.y,a.z,a.w,b.x,b.y,b.z,b.w};
        u32 h[4], l[4];
        #pragma unroll
        for (int i = 0; i < 4; ++i) {
            const float x0 = x[2*i], x1 = x[2*i+1];
            h[i] = pack_trunc(x0, x1);
            const float r0 = x0 - __uint_as_float(__float_as_uint(x0) & 0xFFFF0000u);
            const float r1 = x1 - __uint_as_float(__float_as_uint(x1) & 0xFFFF0000u);
            l[i] = pack_trunc(r0, r1);
        }
        const int kt = s >> 5, r = s & 31, rl = r & 7;
        unsigned short* base = Kc + ((((size_t)bh * NITER + kt) * 32 + r) << 8);
        *(uint4*)(base + (((2*c)     ^ rl) << 3)) = make_uint4(h[0],h[1],h[2],h[3]);
        *(uint4*)(base + (((2*c + 1) ^ rl) << 3)) = make_uint4(l[0],l[1],l[2],l[3]);
    } else {
        const int t  = (blockIdx.x - 4096) * 256 + threadIdx.x;   // 2^18 threads
        const int d  = t & 127;
        const int kt = (t >> 7) & (NITER - 1);
        const int bh = t >> 13;
        const float* src = V + (((size_t)bh * NITER + kt) * BK) * D_DIM + d;
        u32 wv[16];
        #pragma unroll
        for (int i = 0; i < 16; ++i)
            wv[i] = pack_rne(src[(2*i) * D_DIM], src[(2*i+1) * D_DIM]);
        unsigned short* dst = Vt + ((((size_t)bh * NITER + kt) * D_DIM + d) << 5);
        #pragma unroll
        for (int i = 0; i < 4; ++i)
            *(uint4*)(dst + i * 8) = make_uint4(wv[4*i],wv[4*i+1],wv[4*i+2],wv[4*i+3]);
    }
}

// ---------------- hot kernel: K dbuf in LDS, V direct-from-global ----------------
__global__ __launch_bounds__(256, 4)
void attn_fused(const float* __restrict__ Q, const unsigned short* __restrict__ Kc,
                const unsigned short* __restrict__ Vt, const float* __restrict__ SF,
                const int* __restrict__ DP, float* __restrict__ OUT)
{
    __shared__ __align__(16) unsigned short sK[2][32 * 256];    // 2 x 16 KB
    __shared__ __align__(16) unsigned short sP[4 * 16 * 32];    // 4 KB, wave-private

    const int bh   = blockIdx.y;
    const int q0   = blockIdx.x * BQ;
    const int tid  = threadIdx.x;
    const int w    = tid >> 6;
    const int lane = tid & 63;
    const int quad = lane >> 4;
    const int lr   = lane & 15;
    const int rl   = lr & 7;

    const size_t bh_off = (size_t)bh * S_LEN * D_DIM;
    const float LOG2E = 1.4426950408889634f;

    // ---- Q fragments, hi/lo bf16 split (A-frag: lane holds A[m=lr][k=quad*8+j]) ----
    s16x8 qhi[4], qlo[4];
    {
        const int qrow = q0 + w * 16 + lr;
        const float* qr = Q + bh_off + (size_t)qrow * D_DIM + quad * 8;
        #pragma unroll
        for (int d0 = 0; d0 < 4; ++d0) {
            const float4 u0 = *(const float4*)(qr + d0 * 32);
            const float4 u1 = *(const float4*)(qr + d0 * 32 + 4);
            const float x[8] = {u0.x,u0.y,u0.z,u0.w,u1.x,u1.y,u1.z,u1.w};
            union { u32 w4[4]; s16x8 v; } H, L;
            #pragma unroll
            for (int i = 0; i < 4; ++i) {
                const float x0 = x[2*i], x1 = x[2*i+1];
                H.w4[i] = pack_trunc(x0, x1);
                const float r0 = x0 - __uint_as_float(__float_as_uint(x0) & 0xFFFF0000u);
                const float r1 = x1 - __uint_as_float(__float_as_uint(x1) & 0xFFFF0000u);
                L.w4[i] = pack_trunc(r0, r1);
            }
            qhi[d0] = H.v; qlo[d0] = L.v;
        }
    }

    f32x4 Oacc[8] = {};
    float mrow[4], lrow[4];
    #pragma unroll
    for (int r = 0; r < 4; ++r) { mrow[r] = -INFINITY; lrow[r] = 0.f; }

    const int rbase = q0 + w * 16 + quad * 4;
    unsigned short* pw = sP + w * (16 * 32);

    const unsigned short* KtBase = Kc + (((size_t)bh * NITER) << 13);
    const unsigned short* VtBase = Vt + (((size_t)bh * NITER) << 12);

    // ---- prologue: DMA K tile 0 -> buf 0 ----
    #pragma unroll
    for (int i = 0; i < 4; ++i)
        GLOAD16(KtBase + (w * 4 + i) * 512 + lane * 8, &sK[0][(w * 4 + i) * 512]);

    for (int kt = 0; kt < NITER; ++kt) {
        const int p = kt & 1;
        // Publishes sK[p] (its DMA was issued a full iteration ago) and
        // guarantees all waves are done reading sK[1-p] before the prefetch
        // below overwrites it.
        __syncthreads();

        // ---- SF loads for tile kt (issued FIRST: their wait is vmcnt(4),
        //      never draining the K-DMA prefetch behind them) ----
        float sc0[4], sc1[4];
        #pragma unroll
        for (int r = 0; r < 4; ++r) {
            const float* sfr = SF + (size_t)(rbase + r) * S_LEN + kt * BK;
            sc0[r] = sfr[lr] * LOG2E;
            sc1[r] = sfr[16 + lr] * LOG2E;
        }

        // ---- DMA K tile kt+1 into sK[1-p] (issued LAST, drained at next barrier) ----
        if (kt + 1 < NITER) {
            const unsigned short* Kn = KtBase + ((size_t)(kt + 1) << 13);
            #pragma unroll
            for (int i = 0; i < 4; ++i)
                GLOAD16(Kn + (w * 4 + i) * 512 + lane * 8, &sK[1 - p][(w * 4 + i) * 512]);
        }

        // ---- QK^T on sK[p], hi/lo compensated (3 passes) ----
        const unsigned short* sKp = sK[p];
        f32x4 acc[2] = {};
        #pragma unroll
        for (int nt = 0; nt < 2; ++nt) {
            const unsigned short* rowp = sKp + (nt * 16 + lr) * 256;
            #pragma unroll
            for (int d0 = 0; d0 < 4; ++d0) {
                const int uh = (8 * d0 + 2 * quad) ^ rl;
                const s16x8 kh8 = *(const s16x8*)(rowp + (uh << 3));
                const s16x8 kl8 = *(const s16x8*)(rowp + ((uh ^ 1) << 3));
                acc[nt] = __builtin_amdgcn_mfma_f32_16x16x32_bf16(qlo[d0], kh8, acc[nt], 0, 0, 0);
                acc[nt] = __builtin_amdgcn_mfma_f32_16x16x32_bf16(qhi[d0], kl8, acc[nt], 0, 0, 0);
                acc[nt] = __builtin_amdgcn_mfma_f32_16x16x32_bf16(qhi[d0], kh8, acc[nt], 0, 0, 0);
            }
        }

        // ---- online softmax (base-2): DPP max-reduce only; l kept per-lane ----
        float al[4], ps[4];
        bool allone = true;
        #pragma unroll
        for (int r = 0; r < 4; ++r) {
            const float t0 = acc[0][r] * sc0[r];
            const float t1 = acc[1][r] * sc1[r];
            const float mx = row_max16(fmaxf(t0, t1));
            const float mnew = fmaxf(mrow[r], mx);
            al[r] = EXP2(mrow[r] - mnew);
            mrow[r] = mnew;
            const float p0 = EXP2(t0 - mnew);
            const float p1 = EXP2(t1 - mnew);
            ps[r] = p0 + p1;
            const int prow = quad * 4 + r;
            pw[prow * 32 + lr]      = (unsigned short)((__float_as_uint(p0) + 0x8000u) >> 16);
            pw[prow * 32 + 16 + lr] = (unsigned short)((__float_as_uint(p1) + 0x8000u) >> 16);
            allone = allone && (al[r] == 1.0f);
        }
        // wave-uniform fast path: once the running max stabilizes, al==1 for
        // all rows of all lanes -> skip the 36-op rescale
        if (__ballot(allone) != ~0ull) {
            const f32x4 alv = {al[0], al[1], al[2], al[3]};
            #pragma unroll
            for (int dt = 0; dt < 8; ++dt)
                Oacc[dt] *= alv;
            #pragma unroll
            for (int r = 0; r < 4; ++r)
                lrow[r] *= al[r];
        }
        #pragma unroll
        for (int r = 0; r < 4; ++r)
            lrow[r] += ps[r];

        // ---- P·V: pa from wave-private LDS, V B-fragments straight from global ----
        const s16x8 pa = *(const s16x8*)(pw + lr * 32 + quad * 8);
        const unsigned short* vl = VtBase + ((size_t)kt << 12) + lr * 32 + quad * 8;
        #pragma unroll
        for (int dt = 0; dt < 8; ++dt) {
            const s16x8 bv = *(const s16x8*)(vl + dt * 512);   // 16 rows * 32 ushorts
            Oacc[dt] = __builtin_amdgcn_mfma_f32_16x16x32_bf16(pa, bv, Oacc[dt], 0, 0, 0);
        }
    }

    // ---- epilogue: reduce l across the row, normalize, scale, store ----
    const float dpf = (float)DP[0];
    float* ob = OUT + bh_off + (size_t)(q0 + w * 16) * D_DIM;
    #pragma unroll
    for (int r = 0; r < 4; ++r) {
        const float lsum = row_sum16(lrow[r]);
        const float sc = dpf / lsum;
        const int row = quad * 4 + r;
        #pragma unroll
        for (int dt = 0; dt < 8; ++dt)
            ob[(size_t)row * D_DIM + dt * 16 + lr] = Oacc[dt][r] * sc;
    }
}

extern "C" void kernel_launch(void* const* d_in, const int* in_sizes, int n_in,
                              void* d_out, int out_size, void* d_ws, size_t ws_size,
                              hipStream_t stream) {
    const float* q  = (const float*)d_in[0];
    const float* k  = (const float*)d_in[1];
    const float* v  = (const float*)d_in[2];
    const float* sf = (const float*)d_in[3];
    const int*   dp = (const int*)d_in[4];
    float* out = (float*)d_out;

    const size_t kc_ushorts = (size_t)32 * NITER * 32 * 256;   // 33.55 M elems
    unsigned short* Kc = (unsigned short*)d_ws;
    unsigned short* Vt = Kc + kc_ushorts;

    prep_kv<<<5120, 256, 0, stream>>>(k, v, Kc, Vt);
    dim3 grid(S_LEN / BQ, 32);   // (32, 32) = 1024 blocks, 4/CU
    attn_fused<<<grid, dim3(256), 0, stream>>>(q, Kc, Vt, sf, dp, out);
}